// Round 21
// baseline (983.185 us; speedup 1.0000x reference)
//
#include <hip/hip_runtime.h>
#include <cstdint>

#pragma STDC FP_CONTRACT OFF

// ---------------------------------------------------------------------------
// GridCLIP forward: hash-grid encode (16 levels x 8) -> MLP 128->256->256->1024
// Round 21: encode = level-blocked (R20) + R17's 3-pass MLP-friendly body:
// pass1 all 8 corner addresses; pass2 all 16 loads into static-indexed
// float4 e0[8]/e1[8] (16 loads in flight per thread); pass3 ordered
// accumulate. R17 proved this op order bit-identical (same canary). R20's
// level-blocking kept (tables L3-resident); gh level-major. MLP/preps =
// R20-verbatim. Theory: encode was latency/MLP-bound (~2-4 loads in flight),
// not BW-bound -> 16x MLP at 16 waves/CU cuts it ~2x; FETCH unchanged.
// ---------------------------------------------------------------------------

typedef _Float16 f16;
typedef __attribute__((ext_vector_type(8))) _Float16 f16x8;
typedef __attribute__((ext_vector_type(4))) float f32x4;

#define ACT_SCALE 4096.0f
#define INV_ACT_SCALE (1.0f / 4096.0f)

__device__ __forceinline__ void gld16(const void* g, void* l) {
  __builtin_amdgcn_global_load_lds(
      (const __attribute__((address_space(1))) void*)(uintptr_t)g,
      (__attribute__((address_space(3))) void*)(uint32_t)(uintptr_t)l,
      16, 0, 0);
}

// ---------------- grid encode (level-blocked, 3-pass, level-major gh) ------
__global__ __launch_bounds__(256) void grid_encode_kernel(
    const float* __restrict__ x, const float* __restrict__ emb,
    f16* __restrict__ gh, int l0, int nlev, int npts)
{
#pragma clang fp contract(off)
  int g = blockIdx.x * blockDim.x + threadIdx.x;
  if (g >= npts * nlev) return;
  int p = g % npts;          // adjacent threads = adjacent points (coalesced)
  int l = l0 + g / npts;     // one level finishes before the next starts

  float x0 = x[3 * p + 0];
  float x1 = x[3 * p + 1];
  float x2 = x[3 * p + 2];

  // XLA chain (R8-proven): t=(x+10)*0.05f ; u=(t+1)*0.5  (barriers pin u)
  float t0 = (x0 + 10.0f) * 0.05f;
  float t1 = (x1 + 10.0f) * 0.05f;
  float t2 = (x2 + 10.0f) * 0.05f;
  asm volatile("" : "+v"(t0), "+v"(t1), "+v"(t2));
  float u0 = (t0 + 1.0f) * 0.5f;
  float u1 = (t1 + 1.0f) * 0.5f;
  float u2 = (t2 + 1.0f) * 0.5f;
  asm volatile("" : "+v"(u0), "+v"(u1), "+v"(u2));

  float scale = (float)((16 << l) - 1);
  float pos0 = u0 * scale + 0.5f;
  float pos1 = u1 * scale + 0.5f;
  float pos2 = u2 * scale + 0.5f;

  float fb0 = floorf(pos0), fb1 = floorf(pos1), fb2 = floorf(pos2);
  float f0 = pos0 - fb0;
  float f1 = pos1 - fb1;
  float f2 = pos2 - fb2;
  uint32_t px = (uint32_t)fb0, py = (uint32_t)fb1, pz = (uint32_t)fb2;

  uint32_t mask = (l < 3) ? ((4096u << (3 * l)) - 1u) : 2097151u;
  uint32_t off;
  if (l == 0)      off = 0u;
  else if (l == 1) off = 4096u;
  else if (l == 2) off = 36864u;
  else             off = 299008u + (uint32_t)(l - 3) * 2097152u;

  float wx[2] = {1.0f - f0, f0};
  float wy[2] = {1.0f - f1, f1};
  float wz[2] = {1.0f - f2, f2};

  // pass 1: all 8 corner addresses
  uint32_t idxs[8];
#pragma unroll
  for (int c = 0; c < 8; ++c) {
    uint32_t cx = px + (uint32_t)(c & 1);
    uint32_t cy = py + (uint32_t)((c >> 1) & 1);
    uint32_t cz = pz + (uint32_t)((c >> 2) & 1);
    uint32_t h = cx ^ (cy * 2654435761u) ^ (cz * 805459861u);
    idxs[c] = (h & mask) + off;
  }
  // pass 2: issue all 16 loads (static-indexed arrays -> registers)
  float4 e0[8], e1[8];
#pragma unroll
  for (int c = 0; c < 8; ++c) {
    const float4* e = (const float4*)(emb + (size_t)idxs[c] * 8);
    e0[c] = e[0];
    e1[c] = e[1];
  }
  // pass 3: ordered accumulate (identical op order to R17's pass)
  float acc[8];
#pragma unroll
  for (int j = 0; j < 8; ++j) acc[j] = 0.0f;
#pragma unroll
  for (int c = 0; c < 8; ++c) {
    float w = wx[c & 1] * wy[(c >> 1) & 1] * wz[(c >> 2) & 1];
    acc[0] += w * e0[c].x; acc[1] += w * e0[c].y;
    acc[2] += w * e0[c].z; acc[3] += w * e0[c].w;
    acc[4] += w * e1[c].x; acc[5] += w * e1[c].y;
    acc[6] += w * e1[c].z; acc[7] += w * e1[c].w;
  }

  f16x8 o;
#pragma unroll
  for (int j = 0; j < 8; ++j) o[j] = (f16)(acc[j] * ACT_SCALE);
  // level-major: gh[l][p][0..8) — consecutive p -> consecutive 16B stores
  *(f16x8*)&gh[((size_t)l * npts + p) * 8] = o;
}

// ---------------- weight preps ---------------------------------------------
template <int K, int N>
__global__ __launch_bounds__(256) void prep_w(
    const float* __restrict__ W, f16* __restrict__ Wt)
{
  int i = blockIdx.x * 256 + threadIdx.x;
  if (i >= N * K) return;
  int n = i / K, k = i - n * K;
  Wt[i] = (f16)W[(size_t)k * N + n];
}

__global__ __launch_bounds__(256) void prep_w1f(
    const float* __restrict__ W1, f16* __restrict__ Wf1)
{
  int i = blockIdx.x * 256 + threadIdx.x;
  if (i >= 128 * 256) return;
  int e  = i & 7;
  int lr = (i >> 3) & 15;
  int kg = (i >> 7) & 15;
  int q  = i >> 11;
  int n = q * 16 + lr;
  int k = kg * 8 + e;
  Wf1[i] = (f16)W1[(size_t)k * 256 + n];
}

__global__ __launch_bounds__(256) void prep_w2f(
    const float* __restrict__ W2, f16* __restrict__ Wf2)
{
  int i = blockIdx.x * 256 + threadIdx.x;
  if (i >= 256 * 256) return;
  int e  = i & 7;
  int lr = (i >> 3) & 15;
  int kg = (i >> 7) & 31;
  int q  = i >> 12;
  int n = q * 16 + lr;
  int k = kg * 8 + e;
  Wf2[i] = (f16)W2[(size_t)k * 256 + n];
}

// ---------------- fused MLP (R20-verbatim) ---------------------------------
__global__ __launch_bounds__(512) void fused_mlp(
    const f16* __restrict__ gh, const f16* __restrict__ Wf1,
    const float* __restrict__ b1, const f16* __restrict__ Wf2,
    const float* __restrict__ b2, const f16* __restrict__ Wt3,
    const float* __restrict__ b3, float* __restrict__ out,
    int nTotal)
{
  __shared__ alignas(16) f16 H1[128 * 256];  // 64KB h1; W3 ring (3x16KB) in ph3
  __shared__ alignas(16) f16 H2[128 * 256];  // 64KB h2 (gh during ph1)
  __shared__ float B3s[1024];                // 4KB b3 cache

  const int tid  = threadIdx.x;
  const int lane = tid & 63;
  const int wid  = tid >> 6;      // 0..7
  const int bm   = blockIdx.x * 128;
  const int lr   = lane & 15;
  const int lkg  = lane >> 4;     // 0..3

  auto stage3 = [&](int buf, int c) {
#pragma unroll
    for (int s = 0; s < 2; ++s) {
      const int g   = tid + s * 512;
      const int row = g >> 5;                       // col-in-chunk 0..31
      const int sg  = g & 31;
      const int gs  = (sg & 24) | ((sg ^ row) & 7);
      gld16(&Wt3[(size_t)(c * 32 + row) * 256 + gs * 8],
            &H1[buf * 8192 + g * 8]);
    }
  };

  // ---- prologue: gh tile (32KB into H2) + b3 cache.
  // gh is LEVEL-MAJOR: granule gs of row == level gs of point (bm+row).
#pragma unroll
  for (int s = 0; s < 4; ++s) {
    const int g   = tid + s * 512;
    const int row = g >> 4;
    const int sg  = g & 15;
    const int gs  = (sg & 8) | ((sg ^ row) & 7);
    gld16(&gh[((size_t)gs * nTotal + (bm + row)) * 8], &H2[g * 8]);
  }
  B3s[tid] = b3[tid];
  B3s[tid + 512] = b3[tid + 512];
  __syncthreads();

  // ===== phase 1: h1 = relu(gh @ W1 + b1*S) =====
  {
    const int rowg = wid >> 2, colg = wid & 3;
    f16x8 bf1[4][4];
#pragma unroll
    for (int j = 0; j < 4; ++j)
#pragma unroll
      for (int f = 0; f < 4; ++f)
        bf1[j][f] = *(const f16x8*)&Wf1[(((colg * 4 + j) * 16 + f * 4 + lkg) * 16 + lr) * 8];

    f32x4 acc[4][4];
#pragma unroll
    for (int i = 0; i < 4; ++i)
#pragma unroll
      for (int j = 0; j < 4; ++j) acc[i][j] = (f32x4){0.f, 0.f, 0.f, 0.f};

#pragma unroll
    for (int f = 0; f < 4; ++f) {
      f16x8 af[4];
#pragma unroll
      for (int i = 0; i < 4; ++i) {
        const int r  = rowg * 64 + i * 16 + lr;
        const int kg = f * 4 + lkg;
        const int gs = (kg & 8) | ((kg ^ r) & 7);
        af[i] = *(const f16x8*)&H2[r * 128 + gs * 8];
      }
#pragma unroll
      for (int i = 0; i < 4; ++i)
#pragma unroll
        for (int j = 0; j < 4; ++j)
          acc[i][j] = __builtin_amdgcn_mfma_f32_16x16x32_f16(
              af[i], bf1[j][f], acc[i][j], 0, 0, 0);
    }

#pragma unroll
    for (int i = 0; i < 4; ++i)
#pragma unroll
      for (int j = 0; j < 4; ++j) {
        const int col = colg * 64 + j * 16 + lr;
        const float bv = b1[col];
        const int kg = col >> 3, e = col & 7;
#pragma unroll
        for (int q = 0; q < 4; ++q) {
          const int row = rowg * 64 + i * 16 + lkg * 4 + q;
          const int kgs = (kg & 24) | ((kg ^ row) & 7);
          float v = fmaxf(acc[i][j][q] + bv * ACT_SCALE, 0.0f);
          H1[row * 256 + kgs * 8 + e] = (f16)v;
        }
      }
  }
  __syncthreads();

  // ===== phase 2: h2 = relu(h1 @ W2 + b2*S) =====
  {
    const int rowg = wid >> 2, colg = wid & 3;
    f16x8 bf2[4][8];
#pragma unroll
    for (int j = 0; j < 4; ++j)
#pragma unroll
      for (int f = 0; f < 8; ++f)
        bf2[j][f] = *(const f16x8*)&Wf2[(((colg * 4 + j) * 32 + f * 4 + lkg) * 16 + lr) * 8];

    f32x4 acc[4][4];
#pragma unroll
    for (int i = 0; i < 4; ++i)
#pragma unroll
      for (int j = 0; j < 4; ++j) acc[i][j] = (f32x4){0.f, 0.f, 0.f, 0.f};

#pragma unroll
    for (int f = 0; f < 8; ++f) {
      f16x8 af[4];
#pragma unroll
      for (int i = 0; i < 4; ++i) {
        const int r   = rowg * 64 + i * 16 + lr;
        const int kg  = f * 4 + lkg;
        const int kgs = (kg & 24) | ((kg ^ r) & 7);
        af[i] = *(const f16x8*)&H1[r * 256 + kgs * 8];
      }
#pragma unroll
      for (int i = 0; i < 4; ++i)
#pragma unroll
        for (int j = 0; j < 4; ++j)
          acc[i][j] = __builtin_amdgcn_mfma_f32_16x16x32_f16(
              af[i], bf2[j][f], acc[i][j], 0, 0, 0);
    }

#pragma unroll
    for (int i = 0; i < 4; ++i)
#pragma unroll
      for (int j = 0; j < 4; ++j) {
        const int col = colg * 64 + j * 16 + lr;
        const float bv = b2[col];
        const int kg = col >> 3, e = col & 7;
#pragma unroll
        for (int q = 0; q < 4; ++q) {
          const int row = rowg * 64 + i * 16 + lkg * 4 + q;
          const int kgs = (kg & 24) | ((kg ^ row) & 7);
          float v = fmaxf(acc[i][j][q] + bv * ACT_SCALE, 0.0f);
          H2[row * 256 + kgs * 8 + e] = (f16)v;
        }
      }
  }
  __syncthreads();  // h2 visible; H1 now dead -> becomes the W3 ring

  // ===== phase 3: out = h2 @ W3 + b3 — 32 chunks of 32 cols, ring-3 in H1 ==
  f16x8 af3[8];
#pragma unroll
  for (int f = 0; f < 8; ++f) {
    const int r   = wid * 16 + lr;
    const int kg  = f * 4 + lkg;
    const int kgs = (kg & 24) | ((kg ^ r) & 7);
    af3[f] = *(const f16x8*)&H2[r * 256 + kgs * 8];
  }

  stage3(0, 0);
  stage3(1, 1);
  stage3(2, 2);
  __syncthreads();  // full drain: chunks 0-2 certified + published

  auto body3 = [&](int c, int wmode, bool dostage) {
    if (wmode == 18) {
      asm volatile("s_waitcnt vmcnt(18)" ::: "memory");
      __builtin_amdgcn_sched_barrier(0);
    } else if (wmode == 16) {
      asm volatile("s_waitcnt vmcnt(16)" ::: "memory");
      __builtin_amdgcn_sched_barrier(0);
    }
    const int buf = c % 3;
    f16x8 bf3[2][8];
#pragma unroll
    for (int cg = 0; cg < 2; ++cg)
#pragma unroll
      for (int f = 0; f < 8; ++f) {
        const int n   = cg * 16 + lr;
        const int kg  = f * 4 + lkg;
        const int kgs = (kg & 24) | ((kg ^ n) & 7);
        bf3[cg][f] = *(const f16x8*)&H1[buf * 8192 + (n * 32 + kgs) * 8];
      }
    asm volatile("s_waitcnt lgkmcnt(0)" ::: "memory");
    __builtin_amdgcn_sched_barrier(0);
    __builtin_amdgcn_s_barrier();
    __builtin_amdgcn_sched_barrier(0);
    if (dostage) stage3(buf, c + 3);
    f32x4 a[2];
#pragma unroll
    for (int cg = 0; cg < 2; ++cg) {
      a[cg] = (f32x4){0.f, 0.f, 0.f, 0.f};
#pragma unroll
      for (int f = 0; f < 8; ++f)
        a[cg] = __builtin_amdgcn_mfma_f32_16x16x32_f16(af3[f], bf3[cg][f],
                                                       a[cg], 0, 0, 0);
    }
#pragma unroll
    for (int cg = 0; cg < 2; ++cg) {
      const int col = c * 32 + cg * 16 + lr;
      const float bv = B3s[col];
#pragma unroll
      for (int q = 0; q < 4; ++q) {
        const int row = bm + wid * 16 + lkg * 4 + q;
        float v = a[cg][q] * INV_ACT_SCALE + bv;
        size_t grow = (size_t)row;
        float* dst = (col < 512)
                         ? (out + grow * 512 + col)
                         : (out + (size_t)nTotal * 512 + grow * 512 + (col - 512));
        __builtin_nontemporal_store(v, dst);
      }
    }
  };

  body3(0, 18, true);
  body3(1, 18, true);
  for (int c = 2; c <= 28; ++c) body3(c, 18, true);
  body3(29, 18, false);
  body3(30, 16, false);
  body3(31, 16, false);
}

// ---------------- launch ----------------
extern "C" void kernel_launch(void* const* d_in, const int* in_sizes, int n_in,
                              void* d_out, int out_size, void* d_ws, size_t ws_size,
                              hipStream_t stream)
{
  const float* x   = (const float*)d_in[0];
  const float* emb = (const float*)d_in[1];
  const float* W1  = (const float*)d_in[2];
  const float* b1  = (const float*)d_in[3];
  const float* W2  = (const float*)d_in[4];
  const float* b2  = (const float*)d_in[5];
  const float* W3  = (const float*)d_in[6];
  const float* b3  = (const float*)d_in[7];
  float* out = (float*)d_out;

  const int NPTS = in_sizes[0] / 3;  // 262144

  f16* Wf1 = (f16*)d_ws;                 // 128*256 frag-ordered
  f16* Wf2 = Wf1 + 128 * 256;            // 256*256 frag-ordered
  f16* Wt3 = Wf2 + 256 * 256;            // 256*1024 transposed [N][K]
  f16* gh0 = Wt3 + 256 * 1024;           // level-major [16][NPTS][8] f16 (64MB)

  prep_w1f<<<(128 * 256 + 255) / 256, 256, 0, stream>>>(W1, Wf1);
  prep_w2f<<<(256 * 256 + 255) / 256, 256, 0, stream>>>(W2, Wf2);
  prep_w<256, 1024><<<(256 * 1024 + 255) / 256, 256, 0, stream>>>(W3, Wt3);

  // level-blocked encode: 8 dispatches, each group's tables L3-resident
  const int groups[8][2] = {{0, 3}, {3, 2}, {5, 2}, {7, 2},
                            {9, 2}, {11, 2}, {13, 2}, {15, 1}};
  for (int gi = 0; gi < 8; ++gi) {
    const int l0 = groups[gi][0], nl = groups[gi][1];
    const int nthr = NPTS * nl;
    grid_encode_kernel<<<(nthr + 255) / 256, 256, 0, stream>>>(
        x, emb, gh0, l0, nl, NPTS);
  }

  fused_mlp<<<NPTS / 128, 512, 0, stream>>>(gh0, Wf1, b1, Wf2, b2, Wt3, b3,
                                            out, NPTS);
}

// Round 22
// 700.575 us; speedup vs baseline: 1.4034x; 1.4034x over previous
//
#include <hip/hip_runtime.h>
#include <cstdint>

#pragma STDC FP_CONTRACT OFF

// ---------------------------------------------------------------------------
// GridCLIP forward: hash-grid encode (16 levels x 8) -> MLP 128->256->256->1024
// Round 22: R20 config (best, 744us) + encode upgraded to an explicit 2-DEEP
// corner pipeline: all 8 idxs/weights precomputed (VALU, bit-identical),
// named A/B corner buffers, corner c+1's loads emitted BEFORE corner c's
// pacing barrier. Keeps R20's winning pacing (per-corner asm barriers) and
// occupancy (VGPR stays <=64), doubles lookahead. Measured bracket: 1-deep
// 430us (R20) / 8-deep 650us (R21) -> 2-deep targets ~350.
// Accumulate order verbatim -> bit-identical (canary 4.768372e-07).
// MLP / preps / level-blocking / level-major gh = R20-verbatim.
// ---------------------------------------------------------------------------

typedef _Float16 f16;
typedef __attribute__((ext_vector_type(8))) _Float16 f16x8;
typedef __attribute__((ext_vector_type(4))) float f32x4;

#define ACT_SCALE 4096.0f
#define INV_ACT_SCALE (1.0f / 4096.0f)

__device__ __forceinline__ void gld16(const void* g, void* l) {
  __builtin_amdgcn_global_load_lds(
      (const __attribute__((address_space(1))) void*)(uintptr_t)g,
      (__attribute__((address_space(3))) void*)(uint32_t)(uintptr_t)l,
      16, 0, 0);
}

// ---------------- grid encode (level-blocked, 2-deep pipelined) ------------
__global__ __launch_bounds__(256) void grid_encode_kernel(
    const float* __restrict__ x, const float* __restrict__ emb,
    f16* __restrict__ gh, int l0, int nlev, int npts)
{
#pragma clang fp contract(off)
  int g = blockIdx.x * blockDim.x + threadIdx.x;
  if (g >= npts * nlev) return;
  int p = g % npts;          // adjacent threads = adjacent points (coalesced)
  int l = l0 + g / npts;     // one level finishes before the next starts

  float x0 = x[3 * p + 0];
  float x1 = x[3 * p + 1];
  float x2 = x[3 * p + 2];

  // XLA chain (R8-proven): t=(x+10)*0.05f ; u=(t+1)*0.5  (barriers pin u)
  float t0 = (x0 + 10.0f) * 0.05f;
  float t1 = (x1 + 10.0f) * 0.05f;
  float t2 = (x2 + 10.0f) * 0.05f;
  asm volatile("" : "+v"(t0), "+v"(t1), "+v"(t2));
  float u0 = (t0 + 1.0f) * 0.5f;
  float u1 = (t1 + 1.0f) * 0.5f;
  float u2 = (t2 + 1.0f) * 0.5f;
  asm volatile("" : "+v"(u0), "+v"(u1), "+v"(u2));

  float scale = (float)((16 << l) - 1);
  float pos0 = u0 * scale + 0.5f;
  float pos1 = u1 * scale + 0.5f;
  float pos2 = u2 * scale + 0.5f;

  float fb0 = floorf(pos0), fb1 = floorf(pos1), fb2 = floorf(pos2);
  float f0 = pos0 - fb0;
  float f1 = pos1 - fb1;
  float f2 = pos2 - fb2;
  uint32_t px = (uint32_t)fb0, py = (uint32_t)fb1, pz = (uint32_t)fb2;

  uint32_t mask = (l < 3) ? ((4096u << (3 * l)) - 1u) : 2097151u;
  uint32_t off;
  if (l == 0)      off = 0u;
  else if (l == 1) off = 4096u;
  else if (l == 2) off = 36864u;
  else             off = 299008u + (uint32_t)(l - 3) * 2097152u;

  float wx[2] = {1.0f - f0, f0};
  float wy[2] = {1.0f - f1, f1};
  float wz[2] = {1.0f - f2, f2};

  // all 8 corner addresses + weights up front (VALU only; values identical)
  uint32_t idxs[8];
  float wgt[8];
#pragma unroll
  for (int c = 0; c < 8; ++c) {
    uint32_t cx = px + (uint32_t)(c & 1);
    uint32_t cy = py + (uint32_t)((c >> 1) & 1);
    uint32_t cz = pz + (uint32_t)((c >> 2) & 1);
    uint32_t h = cx ^ (cy * 2654435761u) ^ (cz * 805459861u);
    idxs[c] = (h & mask) + off;
    wgt[c] = wx[c & 1] * wy[(c >> 1) & 1] * wz[(c >> 2) & 1];
  }

  float acc[8];
#pragma unroll
  for (int j = 0; j < 8; ++j) acc[j] = 0.0f;

  // 2-deep pipeline: named A/B corner buffers; corner c+1's loads are
  // emitted before corner c's pacing barrier.
  float4 a0, a1, b0, b1;
  {
    const float4* e = (const float4*)(emb + (size_t)idxs[0] * 8);
    a0 = e[0]; a1 = e[1];
  }
#pragma unroll
  for (int c = 0; c < 8; c += 2) {
    if (c + 1 < 8) {
      const float4* e = (const float4*)(emb + (size_t)idxs[c + 1] * 8);
      b0 = e[0]; b1 = e[1];
    }
    {
      float w = wgt[c];
      float m0 = w * a0.x, m1 = w * a0.y, m2 = w * a0.z, m3 = w * a0.w;
      float m4 = w * a1.x, m5 = w * a1.y, m6 = w * a1.z, m7 = w * a1.w;
      asm volatile("" : "+v"(m0), "+v"(m1), "+v"(m2), "+v"(m3),
                        "+v"(m4), "+v"(m5), "+v"(m6), "+v"(m7));
      acc[0] += m0; acc[1] += m1; acc[2] += m2; acc[3] += m3;
      acc[4] += m4; acc[5] += m5; acc[6] += m6; acc[7] += m7;
    }
    if (c + 2 < 8) {
      const float4* e = (const float4*)(emb + (size_t)idxs[c + 2] * 8);
      a0 = e[0]; a1 = e[1];
    }
    {
      float w = wgt[c + 1];
      float m0 = w * b0.x, m1 = w * b0.y, m2 = w * b0.z, m3 = w * b0.w;
      float m4 = w * b1.x, m5 = w * b1.y, m6 = w * b1.z, m7 = w * b1.w;
      asm volatile("" : "+v"(m0), "+v"(m1), "+v"(m2), "+v"(m3),
                        "+v"(m4), "+v"(m5), "+v"(m6), "+v"(m7));
      acc[0] += m0; acc[1] += m1; acc[2] += m2; acc[3] += m3;
      acc[4] += m4; acc[5] += m5; acc[6] += m6; acc[7] += m7;
    }
  }

  f16x8 o;
#pragma unroll
  for (int j = 0; j < 8; ++j) o[j] = (f16)(acc[j] * ACT_SCALE);
  // level-major: gh[l][p][0..8) — consecutive p -> consecutive 16B stores
  *(f16x8*)&gh[((size_t)l * npts + p) * 8] = o;
}

// ---------------- weight preps ---------------------------------------------
template <int K, int N>
__global__ __launch_bounds__(256) void prep_w(
    const float* __restrict__ W, f16* __restrict__ Wt)
{
  int i = blockIdx.x * 256 + threadIdx.x;
  if (i >= N * K) return;
  int n = i / K, k = i - n * K;
  Wt[i] = (f16)W[(size_t)k * N + n];
}

__global__ __launch_bounds__(256) void prep_w1f(
    const float* __restrict__ W1, f16* __restrict__ Wf1)
{
  int i = blockIdx.x * 256 + threadIdx.x;
  if (i >= 128 * 256) return;
  int e  = i & 7;
  int lr = (i >> 3) & 15;
  int kg = (i >> 7) & 15;
  int q  = i >> 11;
  int n = q * 16 + lr;
  int k = kg * 8 + e;
  Wf1[i] = (f16)W1[(size_t)k * 256 + n];
}

__global__ __launch_bounds__(256) void prep_w2f(
    const float* __restrict__ W2, f16* __restrict__ Wf2)
{
  int i = blockIdx.x * 256 + threadIdx.x;
  if (i >= 256 * 256) return;
  int e  = i & 7;
  int lr = (i >> 3) & 15;
  int kg = (i >> 7) & 31;
  int q  = i >> 12;
  int n = q * 16 + lr;
  int k = kg * 8 + e;
  Wf2[i] = (f16)W2[(size_t)k * 256 + n];
}

// ---------------- fused MLP (R20-verbatim) ---------------------------------
__global__ __launch_bounds__(512) void fused_mlp(
    const f16* __restrict__ gh, const f16* __restrict__ Wf1,
    const float* __restrict__ b1, const f16* __restrict__ Wf2,
    const float* __restrict__ b2, const f16* __restrict__ Wt3,
    const float* __restrict__ b3, float* __restrict__ out,
    int nTotal)
{
  __shared__ alignas(16) f16 H1[128 * 256];  // 64KB h1; W3 ring (3x16KB) in ph3
  __shared__ alignas(16) f16 H2[128 * 256];  // 64KB h2 (gh during ph1)
  __shared__ float B3s[1024];                // 4KB b3 cache

  const int tid  = threadIdx.x;
  const int lane = tid & 63;
  const int wid  = tid >> 6;      // 0..7
  const int bm   = blockIdx.x * 128;
  const int lr   = lane & 15;
  const int lkg  = lane >> 4;     // 0..3

  auto stage3 = [&](int buf, int c) {
#pragma unroll
    for (int s = 0; s < 2; ++s) {
      const int g   = tid + s * 512;
      const int row = g >> 5;                       // col-in-chunk 0..31
      const int sg  = g & 31;
      const int gs  = (sg & 24) | ((sg ^ row) & 7);
      gld16(&Wt3[(size_t)(c * 32 + row) * 256 + gs * 8],
            &H1[buf * 8192 + g * 8]);
    }
  };

  // ---- prologue: gh tile (32KB into H2) + b3 cache.
  // gh is LEVEL-MAJOR: granule gs of row == level gs of point (bm+row).
#pragma unroll
  for (int s = 0; s < 4; ++s) {
    const int g   = tid + s * 512;
    const int row = g >> 4;
    const int sg  = g & 15;
    const int gs  = (sg & 8) | ((sg ^ row) & 7);
    gld16(&gh[((size_t)gs * nTotal + (bm + row)) * 8], &H2[g * 8]);
  }
  B3s[tid] = b3[tid];
  B3s[tid + 512] = b3[tid + 512];
  __syncthreads();

  // ===== phase 1: h1 = relu(gh @ W1 + b1*S) =====
  {
    const int rowg = wid >> 2, colg = wid & 3;
    f16x8 bf1[4][4];
#pragma unroll
    for (int j = 0; j < 4; ++j)
#pragma unroll
      for (int f = 0; f < 4; ++f)
        bf1[j][f] = *(const f16x8*)&Wf1[(((colg * 4 + j) * 16 + f * 4 + lkg) * 16 + lr) * 8];

    f32x4 acc[4][4];
#pragma unroll
    for (int i = 0; i < 4; ++i)
#pragma unroll
      for (int j = 0; j < 4; ++j) acc[i][j] = (f32x4){0.f, 0.f, 0.f, 0.f};

#pragma unroll
    for (int f = 0; f < 4; ++f) {
      f16x8 af[4];
#pragma unroll
      for (int i = 0; i < 4; ++i) {
        const int r  = rowg * 64 + i * 16 + lr;
        const int kg = f * 4 + lkg;
        const int gs = (kg & 8) | ((kg ^ r) & 7);
        af[i] = *(const f16x8*)&H2[r * 128 + gs * 8];
      }
#pragma unroll
      for (int i = 0; i < 4; ++i)
#pragma unroll
        for (int j = 0; j < 4; ++j)
          acc[i][j] = __builtin_amdgcn_mfma_f32_16x16x32_f16(
              af[i], bf1[j][f], acc[i][j], 0, 0, 0);
    }

#pragma unroll
    for (int i = 0; i < 4; ++i)
#pragma unroll
      for (int j = 0; j < 4; ++j) {
        const int col = colg * 64 + j * 16 + lr;
        const float bv = b1[col];
        const int kg = col >> 3, e = col & 7;
#pragma unroll
        for (int q = 0; q < 4; ++q) {
          const int row = rowg * 64 + i * 16 + lkg * 4 + q;
          const int kgs = (kg & 24) | ((kg ^ row) & 7);
          float v = fmaxf(acc[i][j][q] + bv * ACT_SCALE, 0.0f);
          H1[row * 256 + kgs * 8 + e] = (f16)v;
        }
      }
  }
  __syncthreads();

  // ===== phase 2: h2 = relu(h1 @ W2 + b2*S) =====
  {
    const int rowg = wid >> 2, colg = wid & 3;
    f16x8 bf2[4][8];
#pragma unroll
    for (int j = 0; j < 4; ++j)
#pragma unroll
      for (int f = 0; f < 8; ++f)
        bf2[j][f] = *(const f16x8*)&Wf2[(((colg * 4 + j) * 32 + f * 4 + lkg) * 16 + lr) * 8];

    f32x4 acc[4][4];
#pragma unroll
    for (int i = 0; i < 4; ++i)
#pragma unroll
      for (int j = 0; j < 4; ++j) acc[i][j] = (f32x4){0.f, 0.f, 0.f, 0.f};

#pragma unroll
    for (int f = 0; f < 8; ++f) {
      f16x8 af[4];
#pragma unroll
      for (int i = 0; i < 4; ++i) {
        const int r   = rowg * 64 + i * 16 + lr;
        const int kg  = f * 4 + lkg;
        const int kgs = (kg & 24) | ((kg ^ r) & 7);
        af[i] = *(const f16x8*)&H1[r * 256 + kgs * 8];
      }
#pragma unroll
      for (int i = 0; i < 4; ++i)
#pragma unroll
        for (int j = 0; j < 4; ++j)
          acc[i][j] = __builtin_amdgcn_mfma_f32_16x16x32_f16(
              af[i], bf2[j][f], acc[i][j], 0, 0, 0);
    }

#pragma unroll
    for (int i = 0; i < 4; ++i)
#pragma unroll
      for (int j = 0; j < 4; ++j) {
        const int col = colg * 64 + j * 16 + lr;
        const float bv = b2[col];
        const int kg = col >> 3, e = col & 7;
#pragma unroll
        for (int q = 0; q < 4; ++q) {
          const int row = rowg * 64 + i * 16 + lkg * 4 + q;
          const int kgs = (kg & 24) | ((kg ^ row) & 7);
          float v = fmaxf(acc[i][j][q] + bv * ACT_SCALE, 0.0f);
          H2[row * 256 + kgs * 8 + e] = (f16)v;
        }
      }
  }
  __syncthreads();  // h2 visible; H1 now dead -> becomes the W3 ring

  // ===== phase 3: out = h2 @ W3 + b3 — 32 chunks of 32 cols, ring-3 in H1 ==
  f16x8 af3[8];
#pragma unroll
  for (int f = 0; f < 8; ++f) {
    const int r   = wid * 16 + lr;
    const int kg  = f * 4 + lkg;
    const int kgs = (kg & 24) | ((kg ^ r) & 7);
    af3[f] = *(const f16x8*)&H2[r * 256 + kgs * 8];
  }

  stage3(0, 0);
  stage3(1, 1);
  stage3(2, 2);
  __syncthreads();  // full drain: chunks 0-2 certified + published

  auto body3 = [&](int c, int wmode, bool dostage) {
    if (wmode == 18) {
      asm volatile("s_waitcnt vmcnt(18)" ::: "memory");
      __builtin_amdgcn_sched_barrier(0);
    } else if (wmode == 16) {
      asm volatile("s_waitcnt vmcnt(16)" ::: "memory");
      __builtin_amdgcn_sched_barrier(0);
    }
    const int buf = c % 3;
    f16x8 bf3[2][8];
#pragma unroll
    for (int cg = 0; cg < 2; ++cg)
#pragma unroll
      for (int f = 0; f < 8; ++f) {
        const int n   = cg * 16 + lr;
        const int kg  = f * 4 + lkg;
        const int kgs = (kg & 24) | ((kg ^ n) & 7);
        bf3[cg][f] = *(const f16x8*)&H1[buf * 8192 + (n * 32 + kgs) * 8];
      }
    asm volatile("s_waitcnt lgkmcnt(0)" ::: "memory");
    __builtin_amdgcn_sched_barrier(0);
    __builtin_amdgcn_s_barrier();
    __builtin_amdgcn_sched_barrier(0);
    if (dostage) stage3(buf, c + 3);
    f32x4 a[2];
#pragma unroll
    for (int cg = 0; cg < 2; ++cg) {
      a[cg] = (f32x4){0.f, 0.f, 0.f, 0.f};
#pragma unroll
      for (int f = 0; f < 8; ++f)
        a[cg] = __builtin_amdgcn_mfma_f32_16x16x32_f16(af3[f], bf3[cg][f],
                                                       a[cg], 0, 0, 0);
    }
#pragma unroll
    for (int cg = 0; cg < 2; ++cg) {
      const int col = c * 32 + cg * 16 + lr;
      const float bv = B3s[col];
#pragma unroll
      for (int q = 0; q < 4; ++q) {
        const int row = bm + wid * 16 + lkg * 4 + q;
        float v = a[cg][q] * INV_ACT_SCALE + bv;
        size_t grow = (size_t)row;
        float* dst = (col < 512)
                         ? (out + grow * 512 + col)
                         : (out + (size_t)nTotal * 512 + grow * 512 + (col - 512));
        __builtin_nontemporal_store(v, dst);
      }
    }
  };

  body3(0, 18, true);
  body3(1, 18, true);
  for (int c = 2; c <= 28; ++c) body3(c, 18, true);
  body3(29, 18, false);
  body3(30, 16, false);
  body3(31, 16, false);
}

// ---------------- launch ----------------
extern "C" void kernel_launch(void* const* d_in, const int* in_sizes, int n_in,
                              void* d_out, int out_size, void* d_ws, size_t ws_size,
                              hipStream_t stream)
{
  const float* x   = (const float*)d_in[0];
  const float* emb = (const float*)d_in[1];
  const float* W1  = (const float*)d_in[2];
  const float* b1  = (const float*)d_in[3];
  const float* W2  = (const float*)d_in[4];
  const float* b2  = (const float*)d_in[5];
  const float* W3  = (const float*)d_in[6];
  const float* b3  = (const float*)d_in[7];
  float* out = (float*)d_out;

  const int NPTS = in_sizes[0] / 3;  // 262144

  f16* Wf1 = (f16*)d_ws;                 // 128*256 frag-ordered
  f16* Wf2 = Wf1 + 128 * 256;            // 256*256 frag-ordered
  f16* Wt3 = Wf2 + 256 * 256;            // 256*1024 transposed [N][K]
  f16* gh0 = Wt3 + 256 * 1024;           // level-major [16][NPTS][8] f16 (64MB)

  prep_w1f<<<(128 * 256 + 255) / 256, 256, 0, stream>>>(W1, Wf1);
  prep_w2f<<<(256 * 256 + 255) / 256, 256, 0, stream>>>(W2, Wf2);
  prep_w<256, 1024><<<(256 * 1024 + 255) / 256, 256, 0, stream>>>(W3, Wt3);

  // level-blocked encode: 8 dispatches, each group's tables L3-resident
  const int groups[8][2] = {{0, 3}, {3, 2}, {5, 2}, {7, 2},
                            {9, 2}, {11, 2}, {13, 2}, {15, 1}};
  for (int gi = 0; gi < 8; ++gi) {
    const int l0 = groups[gi][0], nl = groups[gi][1];
    const int nthr = NPTS * nl;
    grid_encode_kernel<<<(nthr + 255) / 256, 256, 0, stream>>>(
        x, emb, gh0, l0, nl, NPTS);
  }

  fused_mlp<<<NPTS / 128, 512, 0, stream>>>(gh0, Wf1, b1, Wf2, b2, Wt3, b3,
                                            out, NPTS);
}